// Round 4
// baseline (238.494 us; speedup 1.0000x reference)
//
#include <hip/hip_runtime.h>
#include <hip/hip_bf16.h>
#include <stdint.h>

// FP8QDQLinear: out[m,o] = 4 * (q_in @ q_w^T) + bias, q_* exact e4m3 values.
// R4: double-buffered 2-phase pipeline (T3-minimum). Stage NEXT K-tile via
// global_load_lds BEFORE current tile's ds_read+MFMA; single barrier per iter
// whose implicit vmcnt(0) drains next-tile loads AFTER ~700cy of compute.
// MX-scaled fp8 MFMA 16x16x128 (unit E8M0 scales = exact e4m3 math).
// LDS: column-major 16B chunks (slot=col16*128+row), conflict-free (R3: 0),
// global_load_lds dest linear + permutation folded into global src (rule #21).

typedef __attribute__((ext_vector_type(4))) float f32x4;
typedef __attribute__((ext_vector_type(2))) int i32x2;
typedef __attribute__((ext_vector_type(4))) int i32x4;
typedef __attribute__((ext_vector_type(8))) int i32x8;

#define FP8_MAX 448.0f

// ---------------- quantization pass: f32 -> e4m3fn bytes ----------------
__global__ void quant_fp8_kernel(const float* __restrict__ x,
                                 uint32_t* __restrict__ q,
                                 float mul, int n8) {
    int i = blockIdx.x * blockDim.x + threadIdx.x;
    if (i >= n8) return;
    const float4* xv = (const float4*)x;
    float4 v0 = xv[2 * i];
    float4 v1 = xv[2 * i + 1];
    float a[8] = {v0.x, v0.y, v0.z, v0.w, v1.x, v1.y, v1.z, v1.w};
#pragma unroll
    for (int j = 0; j < 8; ++j) {
        float t = a[j] * mul;
        t = fminf(fmaxf(t, -FP8_MAX), FP8_MAX);
        a[j] = t;
    }
    int lo = 0, hi = 0;
    lo = __builtin_amdgcn_cvt_pk_fp8_f32(a[0], a[1], lo, false);
    lo = __builtin_amdgcn_cvt_pk_fp8_f32(a[2], a[3], lo, true);
    hi = __builtin_amdgcn_cvt_pk_fp8_f32(a[4], a[5], hi, false);
    hi = __builtin_amdgcn_cvt_pk_fp8_f32(a[6], a[7], hi, true);
    i32x2 out;
    out.x = lo;
    out.y = hi;
    ((i32x2*)q)[i] = out;
}

// ---------------- MX-fp8 GEMM: C = 4*(A_q @ W_q^T) + bias ----------------
// 128x128 tile, BK=128 bytes, 256 threads = 4 waves (2x2), each wave a 64x64
// output sub-tile = 4x4 fragments of 16x16x128 scaled MFMA.
#define TILE 128
#define BK 128
#define KTILES 32               // K / BK
#define UNIT_SCALE 0x7F7F7F7F   // E8M0 127 = 2^0 in every byte

__device__ static inline void gload_lds16(const void* g, void* l) {
    __builtin_amdgcn_global_load_lds(
        (const __attribute__((address_space(1))) void*)g,
        (__attribute__((address_space(3))) void*)l, 16, 0, 0);
}

__global__ void fp8_gemm_bias_kernel(const uint8_t* __restrict__ Aq,
                                     const uint8_t* __restrict__ Wq,
                                     const float* __restrict__ bias,
                                     float* __restrict__ C,
                                     int M, int N, int K) {
    // double-buffered; each buffer: 1024 chunks of 16B, slot = col16*128 + row
    __shared__ __align__(16) uint8_t sA[2][TILE * BK];
    __shared__ __align__(16) uint8_t sB[2][TILE * BK];

    const int t = threadIdx.x;
    const int lane = t & 63;
    const int w = t >> 6;       // wave 0..3
    const int wr = w >> 1;      // wave row 0..1
    const int wc = w & 1;       // wave col 0..1
    const int lr = lane & 15;   // fragment row within 16
    const int lk = lane >> 4;   // k-group 0..3 (32 bytes each)

    const int bm = blockIdx.y;
    const int bn = blockIdx.x;

    const uint8_t* Abase = Aq + (size_t)(bm * TILE) * K;
    const uint8_t* Bbase = Wq + (size_t)(bn * TILE) * K;

    // staging: pass c stages chunk s = c*256 + t; col16 = c*2 + (t>>7), row = t&127
    const int srow = t & 127;
    const int scol0 = (t >> 7) * 16;   // 0 or 16
    const uint8_t* gaA = Abase + (size_t)srow * K + scol0;
    const uint8_t* gaB = Bbase + (size_t)srow * K + scol0;

    // fragment: lane reads chunks col16 = lk*2, lk*2+1 at row w*64 + m*16 + lr
    const int aoff = lk * 4096 + (wr * 64 + lr) * 16;
    const int boff = lk * 4096 + (wc * 64 + lr) * 16;

    f32x4 acc[4][4];
#pragma unroll
    for (int m = 0; m < 4; ++m)
#pragma unroll
        for (int n = 0; n < 4; ++n)
            acc[m][n] = (f32x4){0.f, 0.f, 0.f, 0.f};

    // prologue: stage K-tile 0 into buffer 0, drain, barrier
#pragma unroll
    for (int c = 0; c < 4; ++c) {
        gload_lds16(gaA + c * 32, sA[0] + c * 4096 + t * 16);
        gload_lds16(gaB + c * 32, sB[0] + c * 4096 + t * 16);
    }
    __syncthreads();  // vmcnt(0) drain + barrier

    int cur = 0;
    for (int kt = 0; kt < KTILES; ++kt) {
        // issue NEXT tile's stages first — they fly during this tile's compute
        if (kt + 1 < KTILES) {
            const int ko = (kt + 1) * BK;
#pragma unroll
            for (int c = 0; c < 4; ++c) {
                gload_lds16(gaA + ko + c * 32, sA[cur ^ 1] + c * 4096 + t * 16);
                gload_lds16(gaB + ko + c * 32, sB[cur ^ 1] + c * 4096 + t * 16);
            }
        }

        // ds_read current tile's fragments
        i32x8 a[4], b[4];
#pragma unroll
        for (int m = 0; m < 4; ++m) {
            i32x4 lo = *(const i32x4*)(sA[cur] + aoff + m * 256);
            i32x4 hi = *(const i32x4*)(sA[cur] + aoff + m * 256 + 2048);
            a[m] = (i32x8){lo[0], lo[1], lo[2], lo[3], hi[0], hi[1], hi[2], hi[3]};
        }
#pragma unroll
        for (int n = 0; n < 4; ++n) {
            i32x4 lo = *(const i32x4*)(sB[cur] + boff + n * 256);
            i32x4 hi = *(const i32x4*)(sB[cur] + boff + n * 256 + 2048);
            b[n] = (i32x8){lo[0], lo[1], lo[2], lo[3], hi[0], hi[1], hi[2], hi[3]};
        }

        __builtin_amdgcn_s_setprio(1);
#pragma unroll
        for (int m = 0; m < 4; ++m)
#pragma unroll
            for (int n = 0; n < 4; ++n)
                acc[m][n] = __builtin_amdgcn_mfma_scale_f32_16x16x128_f8f6f4(
                    a[m], b[n], acc[m][n],
                    0 /*cbsz: A=fp8*/, 0 /*blgp: B=fp8*/,
                    0, UNIT_SCALE, 0, UNIT_SCALE);
        __builtin_amdgcn_s_setprio(0);

        // one barrier per iter: implicit vmcnt(0) waits next-tile stages
        // (issued ~700cy ago) + all waves done reading buf[cur]
        __syncthreads();
        cur ^= 1;
    }

    // epilogue: C/D layout col=lane&15, row=(lane>>4)*4+j (shape-determined)
    const int crow0 = bm * TILE + wr * 64 + lk * 4;
    const int ccol0 = bn * TILE + wc * 64 + lr;
#pragma unroll
    for (int n = 0; n < 4; ++n) {
        const int col = ccol0 + n * 16;
        const float bv = bias[col];
#pragma unroll
        for (int m = 0; m < 4; ++m) {
            const int row = crow0 + m * 16;
#pragma unroll
            for (int j = 0; j < 4; ++j) {
                C[(size_t)(row + j) * N + col] = acc[m][n][j] * 4.0f + bv;
            }
        }
    }
}

extern "C" void kernel_launch(void* const* d_in, const int* in_sizes, int n_in,
                              void* d_out, int out_size, void* d_ws, size_t ws_size,
                              hipStream_t stream) {
    const int M = 4096, N = 4096, K = 4096;
    const float* input  = (const float*)d_in[0];   // [M][K] f32
    const float* weight = (const float*)d_in[1];   // [N][K] f32 (e4m3-grid values)
    const float* bias   = (const float*)d_in[2];   // [N] f32
    float* out = (float*)d_out;                    // [M][N] f32

    uint8_t* Aq = (uint8_t*)d_ws;                        // 16 MiB
    uint8_t* Wq = (uint8_t*)d_ws + (size_t)M * K;        // 16 MiB

    {
        int n8 = (M * K) / 8;
        int blocks = (n8 + 255) / 256;
        quant_fp8_kernel<<<blocks, 256, 0, stream>>>(input, (uint32_t*)Aq, 0.5f, n8);
        quant_fp8_kernel<<<blocks, 256, 0, stream>>>(weight, (uint32_t*)Wq, 1.0f, n8);
    }

    dim3 grid(N / TILE, M / TILE);
    fp8_gemm_bias_kernel<<<grid, 256, 0, stream>>>(Aq, Wq, bias, out, M, N, K);
}

// Round 5
// 124.765 us; speedup vs baseline: 1.9115x; 1.9115x over previous
//
#include <hip/hip_runtime.h>
#include <hip/hip_bf16.h>
#include <stdint.h>

// FP8QDQLinear: out[m,o] = 4 * (q_in @ q_w^T) + bias, q_* exact e4m3 values.
// R5: 256^2 8-phase schedule (T3+T4+T5) ported to MX-fp8 16x16x128.
// 512 thr = 8 waves (2Mx4N), wave output 128x64, BK=128, 2 K-tiles/iter.
// LDS 128 KiB = 2 K-tile buffers x (A 32K + B 32K), column-chunk layout
// (slot = col16*256 + row) -> conflict-free ds_read_b128 (R3-verified).
// Counted vmcnt(2) at phases 4 & 8 only (never 0 in main loop); raw s_barrier.
// Stage ledger (2 calls/phase): p1:A23[k+1]->buf1 p2:B01[k+1] p3:B23[k+1]
// p4:A01[k+2]->buf0 p5:A23[k+2] p6:B01[k+2] p7:B23[k+2] p8:A01[k+3]->buf1.

typedef __attribute__((ext_vector_type(4))) float f32x4;
typedef __attribute__((ext_vector_type(2))) int i32x2;
typedef __attribute__((ext_vector_type(4))) int i32x4;
typedef __attribute__((ext_vector_type(8))) int i32x8;

#define FP8_MAX 448.0f
#define UNIT_SCALE 0x7F7F7F7F  // E8M0 127 = 2^0 in every byte

// ---------------- quantization pass: f32 -> e4m3fn bytes ----------------
__global__ void quant_fp8_kernel(const float* __restrict__ x,
                                 uint32_t* __restrict__ q,
                                 float mul, int n8) {
    int i = blockIdx.x * blockDim.x + threadIdx.x;
    if (i >= n8) return;
    const float4* xv = (const float4*)x;
    float4 v0 = xv[2 * i];
    float4 v1 = xv[2 * i + 1];
    float a[8] = {v0.x, v0.y, v0.z, v0.w, v1.x, v1.y, v1.z, v1.w};
#pragma unroll
    for (int j = 0; j < 8; ++j) {
        float t = a[j] * mul;
        t = fminf(fmaxf(t, -FP8_MAX), FP8_MAX);
        a[j] = t;
    }
    int lo = 0, hi = 0;
    lo = __builtin_amdgcn_cvt_pk_fp8_f32(a[0], a[1], lo, false);
    lo = __builtin_amdgcn_cvt_pk_fp8_f32(a[2], a[3], lo, true);
    hi = __builtin_amdgcn_cvt_pk_fp8_f32(a[4], a[5], hi, false);
    hi = __builtin_amdgcn_cvt_pk_fp8_f32(a[6], a[7], hi, true);
    i32x2 out;
    out.x = lo;
    out.y = hi;
    ((i32x2*)q)[i] = out;
}

// ---------------- MX-fp8 8-phase GEMM: C = 4*(A_q @ W_q^T) + bias ----------
#define KTILES 32  // K / 128

__device__ static inline void gload_lds16(const void* g, void* l) {
    __builtin_amdgcn_global_load_lds(
        (const __attribute__((address_space(1))) void*)g,
        (__attribute__((address_space(3))) void*)l, 16, 0, 0);
}

// stage 2 K-slabs (c0, c0+1) of one operand: 2 x (512 thr x 16B) = 16 KiB
#define STAGE2(GSRC, KB, LBASE, C0)                                        \
    gload_lds16((GSRC) + (KB) + (C0) * 32,       (LBASE) + (C0) * 8192 + t * 16); \
    gload_lds16((GSRC) + (KB) + (C0) * 32 + 32,  (LBASE) + (C0) * 8192 + 8192 + t * 16);

#define READ_A(LBASE, MH)                                                  \
    _Pragma("unroll") for (int m = 0; m < 4; ++m) {                        \
        i32x4 lo = *(const i32x4*)((LBASE) + aoff + (MH) * 1024 + m * 256);       \
        i32x4 hi = *(const i32x4*)((LBASE) + aoff + (MH) * 1024 + m * 256 + 4096);\
        areg[m] = (i32x8){lo[0], lo[1], lo[2], lo[3], hi[0], hi[1], hi[2], hi[3]};\
    }

#define READ_B(LBASE, NH)                                                  \
    _Pragma("unroll") for (int n = 0; n < 2; ++n) {                        \
        i32x4 lo = *(const i32x4*)((LBASE) + boff + (NH) * 512 + n * 256);        \
        i32x4 hi = *(const i32x4*)((LBASE) + boff + (NH) * 512 + n * 256 + 4096); \
        breg[n] = (i32x8){lo[0], lo[1], lo[2], lo[3], hi[0], hi[1], hi[2], hi[3]};\
    }

#define MFMA8(MH, NH)                                                      \
    __builtin_amdgcn_s_setprio(1);                                         \
    _Pragma("unroll") for (int m = 0; m < 4; ++m)                          \
        _Pragma("unroll") for (int n = 0; n < 2; ++n)                      \
            acc[(MH) * 4 + m][(NH) * 2 + n] =                              \
                __builtin_amdgcn_mfma_scale_f32_16x16x128_f8f6f4(          \
                    areg[m], breg[n], acc[(MH) * 4 + m][(NH) * 2 + n],     \
                    0, 0, 0, UNIT_SCALE, 0, UNIT_SCALE);                   \
    __builtin_amdgcn_s_setprio(0);

#define BAR() __builtin_amdgcn_s_barrier()
#define VMW2() asm volatile("s_waitcnt vmcnt(2)" ::: "memory")

__global__ __launch_bounds__(512, 2) void fp8_gemm_bias_kernel(
        const uint8_t* __restrict__ Aq, const uint8_t* __restrict__ Wq,
        const float* __restrict__ bias, float* __restrict__ C,
        int M, int N, int K) {
    __shared__ __align__(16) uint8_t lds[131072];
    uint8_t* const sA0 = lds;           // buf0 A (K-tiles even)
    uint8_t* const sB0 = lds + 32768;   // buf0 B
    uint8_t* const sA1 = lds + 65536;   // buf1 A (K-tiles odd)
    uint8_t* const sB1 = lds + 98304;   // buf1 B

    const int t = threadIdx.x;
    const int lane = t & 63;
    const int w = t >> 6;       // wave 0..7
    const int wr = w >> 2;      // wave row 0..1  (128 rows each)
    const int wc = w & 3;       // wave col 0..3  (64 cols each)
    const int lr = lane & 15;
    const int lk = lane >> 4;   // K-group (32 bytes)

    // XCD-aware swizzle: 256 blocks, 8 XCDs, 32 per XCD -> contiguous bm rows
    const int bid = blockIdx.x;
    const int swz = (bid & 7) * 32 + (bid >> 3);
    const int bm = swz >> 4;
    const int bn = swz & 15;

    const uint8_t* Abase = Aq + (size_t)(bm * 256) * K;
    const uint8_t* Bbase = Wq + (size_t)(bn * 256) * K;

    // staging source: thread t covers slot 512c+t of slab c:
    // row = t&255, col16 = 2c + (t>>8); src = row*K + kb + col16*16
    const int srow = t & 255;
    const int scol = (t >> 8) * 16;
    const uint8_t* gA = Abase + (size_t)srow * K + scol;
    const uint8_t* gB = Bbase + (size_t)srow * K + scol;

    // fragment read bases (within an operand's 32 KiB region):
    // A row r = wr*128 + mh*64 + m*16 + lr, col16 pair (2lk, 2lk+1)
    const int aoff = lk * 8192 + wr * 2048 + lr * 16;
    const int boff = lk * 8192 + wc * 1024 + lr * 16;

    f32x4 acc[8][4];
#pragma unroll
    for (int mi = 0; mi < 8; ++mi)
#pragma unroll
        for (int ni = 0; ni < 4; ++ni)
            acc[mi][ni] = (f32x4){0.f, 0.f, 0.f, 0.f};

    i32x8 areg[4], breg[2];

    // ---- prologue: K-tile 0 -> buf0 (8 calls), K-tile 1 A01 -> buf1 (2) ----
    STAGE2(gA, 0, sA0, 0)
    STAGE2(gA, 0, sA0, 2)
    STAGE2(gB, 0, sB0, 0)
    STAGE2(gB, 0, sB0, 2)
    STAGE2(gA, 128, sA1, 0)
    VMW2();            // oldest 8 (all of K-tile 0) complete; K1 A01 in flight
    BAR();

    for (int it = 0; it < KTILES / 2; ++it) {
        const int kb1 = (2 * it + 1) * 128;            // K-tile into buf1 (finish)
        const int kb2 = ((2 * it + 2) & 31) * 128;     // K-tile into buf0
        const int kb3 = ((2 * it + 3) & 31) * 128;     // K-tile into buf1 (start)

        // ---- phases 1-4: compute buf0 (K-tile 2it) ----
        // p1: quad(0,0)
        READ_A(sA0, 0)
        READ_B(sB0, 0)
        STAGE2(gA, kb1, sA1, 2)
        BAR();
        MFMA8(0, 0)
        BAR();
        // p2: quad(0,1)  (A mh=0 kept in regs)
        READ_B(sB0, 1)
        STAGE2(gB, kb1, sB1, 0)
        BAR();
        MFMA8(0, 1)
        BAR();
        // p3: quad(1,0)
        READ_A(sA0, 1)
        READ_B(sB0, 0)
        STAGE2(gB, kb1, sB1, 2)
        BAR();
        MFMA8(1, 0)
        BAR();
        // p4: quad(1,1); guard buf1 for phases 5-8
        READ_B(sB0, 1)
        STAGE2(gA, kb2, sA0, 0)
        BAR();
        MFMA8(1, 1)
        VMW2();   // completes [p8', p1, p2, p3] = all of buf1's K-tile
        BAR();

        // ---- phases 5-8: compute buf1 (K-tile 2it+1) ----
        // p5: quad(0,0)
        READ_A(sA1, 0)
        READ_B(sB1, 0)
        STAGE2(gA, kb2, sA0, 2)
        BAR();
        MFMA8(0, 0)
        BAR();
        // p6: quad(0,1)
        READ_B(sB1, 1)
        STAGE2(gB, kb2, sB0, 0)
        BAR();
        MFMA8(0, 1)
        BAR();
        // p7: quad(1,0)
        READ_A(sA1, 1)
        READ_B(sB1, 0)
        STAGE2(gB, kb2, sB0, 2)
        BAR();
        MFMA8(1, 0)
        BAR();
        // p8: quad(1,1); guard buf0 for next iteration
        READ_B(sB1, 1)
        STAGE2(gA, kb3, sA1, 0)
        BAR();
        MFMA8(1, 1)
        VMW2();   // completes [p4..p7] = all of buf0's next K-tile
        BAR();
    }

    // ---- epilogue: C/D layout col=lane&15, row=(lane>>4)*4+j ----
    const int crow0 = bm * 256 + wr * 128 + lk * 4;
    const int ccol0 = bn * 256 + wc * 64 + lr;
#pragma unroll
    for (int ni = 0; ni < 4; ++ni) {
        const int col = ccol0 + ni * 16;
        const float bv = bias[col];
#pragma unroll
        for (int mi = 0; mi < 8; ++mi) {
            const int row = crow0 + mi * 16;
#pragma unroll
            for (int j = 0; j < 4; ++j) {
                C[(size_t)(row + j) * N + col] = acc[mi][ni][j] * 4.0f + bv;
            }
        }
    }
}

extern "C" void kernel_launch(void* const* d_in, const int* in_sizes, int n_in,
                              void* d_out, int out_size, void* d_ws, size_t ws_size,
                              hipStream_t stream) {
    const int M = 4096, N = 4096, K = 4096;
    const float* input  = (const float*)d_in[0];   // [M][K] f32
    const float* weight = (const float*)d_in[1];   // [N][K] f32 (e4m3-grid values)
    const float* bias   = (const float*)d_in[2];   // [N] f32
    float* out = (float*)d_out;                    // [M][N] f32

    uint8_t* Aq = (uint8_t*)d_ws;                        // 16 MiB
    uint8_t* Wq = (uint8_t*)d_ws + (size_t)M * K;        // 16 MiB

    {
        int n8 = (M * K) / 8;
        int blocks = (n8 + 255) / 256;
        quant_fp8_kernel<<<blocks, 256, 0, stream>>>(input, (uint32_t*)Aq, 0.5f, n8);
        quant_fp8_kernel<<<blocks, 256, 0, stream>>>(weight, (uint32_t*)Wq, 1.0f, n8);
    }

    dim3 grid(256);  // (M/256) x (N/256), XCD-swizzled in-kernel
    fp8_gemm_bias_kernel<<<grid, 512, 0, stream>>>(Aq, Wq, bias, out, M, N, K);
}